// Round 10
// baseline (329.794 us; speedup 1.0000x reference)
//
#include <hip/hip_runtime.h>
#include <hip/hip_cooperative_groups.h>
#include <math.h>

namespace cg = cooperative_groups;

#define BB 32
#define RR 2000
#define CC 81
#define CM1 80
#define TROWS 64
#define NTILE 32
#define NTILES_TOTAL 1024    // BB * NTILE
#define CAP 28
#define SCAP 896             // NTILE * CAP
#define NCOLS 2560           // BB * CM1
#define NZ4_TOTAL 7680000    // (dets 25.6M + sv 5.12M) / 4 float4s
#define NZ4_P1 4500000       // zero-front done in P1 (overlaps compact)

// ---------------------------------------------------------------------------
// One kernel, three phases. phase==3: cooperative, grid.sync between phases.
// phase==0/1/2: same code split across 3 normal launches (fallback).
//   P1: ballot-compact cls -> per-(col,tile) pairs+counts  ||  zero-front
//   P2: per-column gather + sort (reg-bitonic n<=64 / LDS) ||  zero-tail
//   P3: scatter-decode valid prefix into dets/sv + row softmax
// ---------------------------------------------------------------------------
__global__ __launch_bounds__(256, 6) void fused_kernel(
    const float* __restrict__ rois,   // (B, R, 5)
    const float* __restrict__ cls,    // (B, R, 81)
    const float* __restrict__ bbox,   // (B, R, 324)
    float* __restrict__ dets,         // (B, R, 80, 5)
    float* __restrict__ sv,           // (B, R, 80)
    float* __restrict__ dist,         // (B, R, 81)
    float* __restrict__ maxs,         // (B*R,)
    float* __restrict__ labels,       // (B*R,)
    int* __restrict__ counts,         // (2560, NTILE)
    float2* __restrict__ pairs,       // (2560, SCAP)
    int* __restrict__ ncol,           // (2560,)
    int nblocks, int phase)
{
    __shared__ float smem[5280];      // 21,120 B, reused by P1 tile / P2 sort

    const int tid  = threadIdx.x;
    const int bid  = blockIdx.x;
    const int wave = tid >> 6;
    const int lane = tid & 63;
    const long long T = (long long)nblocks * 256;

    // ===================== P1: compact + zero-front =====================
    if (phase == 3 || phase == 0) {
        for (int t = bid; t < NTILES_TOTAL; t += nblocks) {
            const int b  = t >> 5;
            const int tt = t & 31;
            const int r0 = tt * TROWS;
            const int nr = (RR - r0 < TROWS) ? (RR - r0) : TROWS;
            __syncthreads();
            const float* src = cls + (size_t)(b * RR + r0) * CC;
            for (int i = tid; i < nr * CC; i += 256) {
                int rl = i / CC, c = i - rl * CC;
                smem[c * (TROWS + 1) + rl] = src[i];
            }
            __syncthreads();
            for (int q = 0; q < 20; ++q) {
                const int c   = 1 + wave + 4 * q;          // classes 1..80
                const int col = b * CM1 + (c - 1);
                float s = smem[c * (TROWS + 1) + lane];
                bool valid = (lane < nr) && (s > 0.1f);
                unsigned long long mask = __ballot(valid);
                if (valid) {
                    int pos = __popcll(mask & ((1ull << lane) - 1ull));
                    if (pos < CAP)
                        pairs[(size_t)col * SCAP + tt * CAP + pos] =
                            make_float2(s, __int_as_float(r0 + lane));
                }
                if (lane == 0) {
                    int cnt = (int)__popcll(mask);
                    counts[col * NTILE + tt] = (cnt < CAP) ? cnt : CAP;
                }
            }
        }
        float4* z = (float4*)dets;    // dets then sv, contiguous
        const float4 z4 = make_float4(0.f, 0.f, 0.f, 0.f);
        for (long long i = (long long)bid * 256 + tid; i < NZ4_P1; i += T)
            z[i] = z4;
    }
    if (phase == 3) cg::this_grid().sync();

    // ===================== P2: zero-tail + sort =====================
    if (phase == 3 || phase == 1) {
        {
            float4* z = (float4*)dets;
            const float4 z4 = make_float4(0.f, 0.f, 0.f, 0.f);
            for (long long i = NZ4_P1 + (long long)bid * 256 + tid; i < NZ4_TOTAL; i += T)
                z[i] = z4;
        }
        float* ssc   = smem;                   // 1024 f
        int*   sidx  = (int*)(smem + 1024);    // 1024 i
        int*   scnt  = (int*)(smem + 2048);    // 32 i
        int*   spref = (int*)(smem + 2112);    // 33 i
        for (int col = bid; col < NCOLS; col += nblocks) {
            __syncthreads();
            if (tid < NTILE) scnt[tid] = counts[col * NTILE + tid];
            __syncthreads();
            if (tid == 0) {
                int a = 0;
                for (int t = 0; t < NTILE; ++t) { spref[t] = a; a += scnt[t]; }
                spref[NTILE] = a;
                ncol[col] = a;
            }
            __syncthreads();
            const int n = spref[NTILE];        // <= 896
            float2* pbase = pairs + (size_t)col * SCAP;
            for (int t = wave; t < NTILE; t += 4) {
                int cnt = scnt[t];
                for (int k = lane; k < cnt; k += 64) {
                    float2 e = pbase[t * CAP + k];
                    int pos = spref[t] + k;
                    ssc[pos]  = e.x;
                    sidx[pos] = __float_as_int(e.y);
                }
            }
            __syncthreads();
            if (n > 1) {
                if (n <= 64) {
                    if (wave == 0) {
                        float s  = (lane < n) ? ssc[lane]  : -INFINITY;
                        int   id = (lane < n) ? sidx[lane] : 0x7FFFFFFF;
                        #pragma unroll
                        for (int k = 2; k <= 64; k <<= 1) {
                            #pragma unroll
                            for (int jj = k >> 1; jj > 0; jj >>= 1) {
                                float os = __shfl_xor(s, jj);
                                int   oi = __shfl_xor(id, jj);
                                bool mineFirst = (s > os) || (s == os && id < oi);
                                bool iLower = ((lane & jj) == 0);
                                bool up = ((lane & k) == 0);
                                bool keep = up ? (mineFirst == iLower)
                                               : (mineFirst != iLower);
                                if (!keep) { s = os; id = oi; }
                            }
                        }
                        if (lane < n) { ssc[lane] = s; sidx[lane] = id; }
                    }
                    __syncthreads();
                } else {
                    int n2 = 1;
                    while (n2 < n) n2 <<= 1;   // <= 1024
                    for (int i = n + tid; i < n2; i += 256) {
                        ssc[i]  = -INFINITY;
                        sidx[i] = 0x7FFFFFFF;
                    }
                    __syncthreads();
                    for (int k = 2; k <= n2; k <<= 1) {
                        for (int jj = k >> 1; jj > 0; jj >>= 1) {
                            for (int i = tid; i < n2; i += 256) {
                                int ixj = i ^ jj;
                                if (ixj > i) {
                                    float si = ssc[i], sx = ssc[ixj];
                                    int   ii = sidx[i], ix = sidx[ixj];
                                    bool before = (si > sx) || (si == sx && ii < ix);
                                    bool doswap = ((i & k) == 0) ? !before : before;
                                    if (doswap) {
                                        ssc[i] = sx; ssc[ixj] = si;
                                        sidx[i] = ix; sidx[ixj] = ii;
                                    }
                                }
                            }
                            __syncthreads();
                        }
                    }
                }
            }
            for (int i = tid; i < n; i += 256)
                pbase[i] = make_float2(ssc[i], __int_as_float(sidx[i]));
        }
    }
    if (phase == 3) cg::this_grid().sync();

    // ===================== P3: scatter decode + softmax =====================
    if (phase == 3 || phase == 2) {
        for (int col = bid; col < NCOLS; col += nblocks) {
            const int b = col / CM1;
            const int j = col - b * CM1;
            const int n = ncol[col];
            const float2* pbase = pairs + (size_t)col * SCAP;
            for (int i = tid; i < n; i += 256) {
                float2 e = pbase[i];
                float sc = e.x;
                int   r  = __float_as_int(e.y);
                const float* rp = rois + (size_t)(b * RR + r) * 5;
                float x1 = rp[1], y1 = rp[2], x2 = rp[3], y2 = rp[4];
                float w  = x2 - x1 + 1.0f;
                float h  = y2 - y1 + 1.0f;
                float cx = x1 + 0.5f * w;
                float cy = y1 + 0.5f * h;
                const float* dp = bbox + (size_t)(b * RR + r) * (4 * CC) + 4 * (j + 1);
                float dx = dp[0] * 0.1f, dy = dp[1] * 0.1f;
                float dw = dp[2] * 0.2f, dh = dp[3] * 0.2f;
                float pcx = dx * w + cx;
                float pcy = dy * h + cy;
                float pw  = expf(dw) * w;
                float ph  = expf(dh) * h;
                size_t obase = ((size_t)(b * RR + i) * CM1 + j) * 5;
                dets[obase + 0] = fmaxf(pcx - 0.5f * pw, 0.0f);
                dets[obase + 1] = fmaxf(pcy - 0.5f * ph, 0.0f);
                dets[obase + 2] = fmaxf(pcx + 0.5f * pw - 1.0f, 0.0f);
                dets[obase + 3] = fmaxf(pcy + 0.5f * ph - 1.0f, 0.0f);
                dets[obase + 4] = sc;
                sv[(size_t)(b * RR + i) * CM1 + j] = 1.0f;
            }
        }
        for (int rb = bid; rb < (BB * RR) / 4; rb += nblocks) {
            const int row = rb * 4 + wave;
            const float* in = cls + (size_t)row * CC;
            float v0 = in[lane];
            float v1 = (lane < CC - 64) ? in[64 + lane] : -INFINITY;
            float m  = v0;
            int   mi = lane;
            if (v1 > m) { m = v1; mi = 64 + lane; }
            for (int off = 32; off > 0; off >>= 1) {
                float om  = __shfl_xor(m, off);
                int   omi = __shfl_xor(mi, off);
                if (om > m || (om == m && omi < mi)) { m = om; mi = omi; }
            }
            float e0 = expf(v0 - m);
            float e1 = (lane < CC - 64) ? expf(v1 - m) : 0.0f;
            float s  = e0 + e1;
            for (int off = 32; off > 0; off >>= 1) s += __shfl_xor(s, off);
            float inv = 1.0f / s;
            float* outd = dist + (size_t)row * CC;
            outd[lane] = e0 * inv;
            if (lane < CC - 64) outd[64 + lane] = e1 * inv;
            if (lane == 0) {
                maxs[row]   = inv;
                labels[row] = (float)mi;
            }
        }
    }
}

extern "C" void kernel_launch(void* const* d_in, const int* in_sizes, int n_in,
                              void* d_out, int out_size, void* d_ws, size_t ws_size,
                              hipStream_t stream) {
    const float* rois = (const float*)d_in[0];   // B*R*5
    const float* cls  = (const float*)d_in[1];   // B*R*81
    const float* bbox = (const float*)d_in[2];   // B*R*324

    float* out = (float*)d_out;
    const size_t sv_off   = (size_t)BB * RR * CM1 * 5;         // 25,600,000
    const size_t dist_off = sv_off + (size_t)BB * RR * CM1;    // 30,720,000
    const size_t maxs_off = dist_off + (size_t)BB * RR * CC;   // 35,904,000
    const size_t lab_off  = maxs_off + (size_t)BB * RR;        // 35,968,000

    float* dets   = out;
    float* sv     = out + sv_off;
    float* dist   = out + dist_off;
    float* maxs   = out + maxs_off;
    float* labels = out + lab_off;

    int*    counts = (int*)d_ws;
    float2* pairs  = (float2*)((char*)d_ws + (size_t)NCOLS * NTILE * sizeof(int));
    int*    ncol   = (int*)((char*)pairs + (size_t)NCOLS * SCAP * sizeof(float2));

    // Grid sized to co-resident capacity (host code runs only at capture).
    int occ = 0;
    hipError_t qe = hipOccupancyMaxActiveBlocksPerMultiprocessor(&occ, fused_kernel, 256, 0);
    int nblocks = (qe == hipSuccess && occ > 0) ? occ * 256 : 1024;  // 256 CUs
    if (nblocks > 1792) nblocks = 1792;

    int phase = 3;
    void* args[] = {(void*)&rois, (void*)&cls, (void*)&bbox,
                    (void*)&dets, (void*)&sv, (void*)&dist, (void*)&maxs, (void*)&labels,
                    (void*)&counts, (void*)&pairs, (void*)&ncol,
                    (void*)&nblocks, (void*)&phase};
    hipError_t le = hipLaunchCooperativeKernel(fused_kernel, dim3(nblocks), dim3(256),
                                               args, 0u, stream);
    if (le != hipSuccess) {
        // Fallback: 3 sequential launches (kernel boundaries replace grid.sync).
        const int nb = 1024;
        fused_kernel<<<nb, 256, 0, stream>>>(rois, cls, bbox, dets, sv, dist, maxs,
                                             labels, counts, pairs, ncol, nb, 0);
        fused_kernel<<<nb, 256, 0, stream>>>(rois, cls, bbox, dets, sv, dist, maxs,
                                             labels, counts, pairs, ncol, nb, 1);
        fused_kernel<<<nb, 256, 0, stream>>>(rois, cls, bbox, dets, sv, dist, maxs,
                                             labels, counts, pairs, ncol, nb, 2);
    }
}

// Round 11
// 51.278 us; speedup vs baseline: 6.4315x; 6.4315x over previous
//
#include <hip/hip_runtime.h>
#include <hip/hip_bf16.h>
#include <math.h>

#define BB 32
#define RR 2000
#define CC 81
#define CM1 80
#define TROWS 64
#define NTILE 32            // tiles per batch (32 * 64 = 2048 >= 2000)
#define NTILES_TOTAL 1024   // BB * NTILE
#define CAP 28              // max stored pairs per (column, tile)
#define SCAP (NTILE * CAP)  // 896

// ---------------------------------------------------------------------------
// K1 (block-specialized): grid = 1024 compact-blocks + 16,000 prep-blocks.
//   compact (bid < 1024): stage 64-row tile in LDS, ballot-compact per class
//     -> counts/pairs. Latency-bound; overlaps prep's store stream.
//   prep (bid >= 1024): zero 480 float4 of dets+sv, 4 waves x 1 row softmax
//     -> dist/maxs/labels. BW-bound (the 27 us floor).
// ---------------------------------------------------------------------------
__global__ __launch_bounds__(256) void fused1_kernel(
    const float* __restrict__ cls,   // (B, R, 81)
    float* __restrict__ dist,        // (B*R, 81)
    float* __restrict__ maxs,        // (B*R,)
    float* __restrict__ labels,      // (B*R,)
    float4* __restrict__ zbase,      // dets start: 30,720,000 floats to zero
    int* __restrict__ counts,        // (2560, NTILE)
    float2* __restrict__ pairs)      // (2560, SCAP)
{
    __shared__ float tile[CC * (TROWS + 1)];
    const int tid  = threadIdx.x;
    const int wave = tid >> 6;
    const int lane = tid & 63;

    if (blockIdx.x < NTILES_TOTAL) {
        // ---------------- compact path ----------------
        const int b   = blockIdx.x >> 5;
        const int tr  = blockIdx.x & 31;
        const int r0  = tr * TROWS;
        const int nr  = (RR - r0 < TROWS) ? (RR - r0) : TROWS;

        const float* src = cls + (size_t)(b * RR + r0) * CC;
        for (int i = tid; i < nr * CC; i += 256) {
            int rl = i / CC, c = i - rl * CC;
            tile[c * (TROWS + 1) + rl] = src[i];
        }
        __syncthreads();

        #pragma unroll 4
        for (int q = 0; q < 20; ++q) {
            const int c   = 1 + wave + 4 * q;          // classes 1..80
            const int col = b * CM1 + (c - 1);
            float s = tile[c * (TROWS + 1) + lane];
            bool valid = (lane < nr) && (s > 0.1f);
            unsigned long long mask = __ballot(valid);
            if (valid) {
                int pos = __popcll(mask & ((1ull << lane) - 1ull));
                if (pos < CAP)
                    pairs[(size_t)col * SCAP + tr * CAP + pos] =
                        make_float2(s, __int_as_float(r0 + lane));
            }
            if (lane == 0) {
                int cnt = (int)__popcll(mask);
                counts[col * NTILE + tr] = (cnt < CAP) ? cnt : CAP;
            }
        }
        return;
    }

    // ---------------- prep path ----------------
    const int pb = blockIdx.x - NTILES_TOTAL;   // 0..15999

    const float4 z4 = make_float4(0.0f, 0.0f, 0.0f, 0.0f);
    const int zb = pb * 480;
    zbase[zb + tid] = z4;
    if (tid < 224) zbase[zb + 256 + tid] = z4;

    const int row = pb * 4 + wave;

    const float* in = cls + (size_t)row * CC;
    float v0 = in[lane];
    float v1 = (lane < CC - 64) ? in[64 + lane] : -INFINITY;

    float m  = v0;
    int   mi = lane;
    if (v1 > m) { m = v1; mi = 64 + lane; }

    for (int off = 32; off > 0; off >>= 1) {
        float om  = __shfl_xor(m, off);
        int   omi = __shfl_xor(mi, off);
        if (om > m || (om == m && omi < mi)) { m = om; mi = omi; }
    }

    float e0 = expf(v0 - m);
    float e1 = (lane < CC - 64) ? expf(v1 - m) : 0.0f;
    float s  = e0 + e1;
    for (int off = 32; off > 0; off >>= 1) s += __shfl_xor(s, off);

    float inv = 1.0f / s;
    float* out = dist + (size_t)row * CC;
    out[lane] = e0 * inv;
    if (lane < CC - 64) out[64 + lane] = e1 * inv;
    if (lane == 0) {
        maxs[row]   = inv;
        labels[row] = (float)mi;
    }
}

// ---------------------------------------------------------------------------
// K2 (sort+decode): one block per (b, class-1) column. Gather compact
// segments into LDS (prefix offsets), sort by (score desc, row asc) —
// register bitonic n<=64 / LDS bitonic otherwise — decode, write valid
// prefix only (rest pre-zeroed by K1's prep blocks).
// ---------------------------------------------------------------------------
__global__ __launch_bounds__(256) void sort_decode_kernel(
    const float* __restrict__ rois,   // (B, R, 5)
    const float* __restrict__ bbox,   // (B, R, 4*C)
    const int* __restrict__ counts,   // (2560, NTILE)
    const float2* __restrict__ pairs, // (2560, SCAP)
    float* __restrict__ dets,         // (B, R, 80, 5), pre-zeroed
    float* __restrict__ sv)           // (B, R, 80), pre-zeroed
{
    __shared__ float ssc[1024];
    __shared__ int   sidx[1024];
    __shared__ int   scnt[NTILE];
    __shared__ int   spref[NTILE + 1];

    const int bj  = blockIdx.x;
    const int b   = bj / CM1;
    const int j   = bj % CM1;
    const int tid = threadIdx.x;
    const int cls_col = j + 1;

    if (tid < NTILE) scnt[tid] = counts[bj * NTILE + tid];
    __syncthreads();
    if (tid == 0) {
        int a = 0;
        for (int t = 0; t < NTILE; ++t) { spref[t] = a; a += scnt[t]; }
        spref[NTILE] = a;
    }
    __syncthreads();

    const int n = spref[NTILE];
    if (n == 0) return;

    const int wave = tid >> 6;
    const int lane = tid & 63;
    const float2* pbase = pairs + (size_t)bj * SCAP;
    for (int t = wave; t < NTILE; t += 4) {
        int cnt = scnt[t];
        for (int k = lane; k < cnt; k += 64) {
            float2 e = pbase[t * CAP + k];
            int pos = spref[t] + k;
            ssc[pos]  = e.x;
            sidx[pos] = __float_as_int(e.y);
        }
    }
    __syncthreads();

    if (n > 1) {
        if (n <= 64) {
            if (wave == 0) {
                float s  = (lane < n) ? ssc[lane]  : -INFINITY;
                int   id = (lane < n) ? sidx[lane] : 0x7FFFFFFF;
                #pragma unroll
                for (int k = 2; k <= 64; k <<= 1) {
                    #pragma unroll
                    for (int jj = k >> 1; jj > 0; jj >>= 1) {
                        float os = __shfl_xor(s, jj);
                        int   oi = __shfl_xor(id, jj);
                        bool mineFirst = (s > os) || (s == os && id < oi);
                        bool iLower = ((lane & jj) == 0);
                        bool up = ((lane & k) == 0);
                        bool keep = up ? (mineFirst == iLower)
                                       : (mineFirst != iLower);
                        if (!keep) { s = os; id = oi; }
                    }
                }
                if (lane < n) { ssc[lane] = s; sidx[lane] = id; }
            }
            __syncthreads();
        } else {
            int n2 = 1;
            while (n2 < n) n2 <<= 1;
            for (int i = n + tid; i < n2; i += 256) {
                ssc[i]  = -INFINITY;
                sidx[i] = 0x7FFFFFFF;
            }
            __syncthreads();
            for (int k = 2; k <= n2; k <<= 1) {
                for (int jj = k >> 1; jj > 0; jj >>= 1) {
                    for (int i = tid; i < n2; i += 256) {
                        int ixj = i ^ jj;
                        if (ixj > i) {
                            float si = ssc[i], sx = ssc[ixj];
                            int   ii = sidx[i], ix = sidx[ixj];
                            bool before = (si > sx) || (si == sx && ii < ix);
                            bool doswap = ((i & k) == 0) ? !before : before;
                            if (doswap) {
                                ssc[i] = sx; ssc[ixj] = si;
                                sidx[i] = ix; sidx[ixj] = ii;
                            }
                        }
                    }
                    __syncthreads();
                }
            }
        }
    }

    for (int i = tid; i < n; i += 256) {
        size_t obase = ((size_t)(b * RR + i) * CM1 + j) * 5;
        int   r = sidx[i];
        float s = ssc[i];
        const float* rp = rois + (size_t)(b * RR + r) * 5;
        float x1 = rp[1], y1 = rp[2], x2 = rp[3], y2 = rp[4];
        float w  = x2 - x1 + 1.0f;
        float h  = y2 - y1 + 1.0f;
        float cx = x1 + 0.5f * w;
        float cy = y1 + 0.5f * h;
        const float* dp = bbox + (size_t)(b * RR + r) * (4 * CC) + 4 * cls_col;
        float dx = dp[0] * 0.1f, dy = dp[1] * 0.1f;
        float dw = dp[2] * 0.2f, dh = dp[3] * 0.2f;
        float pcx = dx * w + cx;
        float pcy = dy * h + cy;
        float pw  = expf(dw) * w;
        float ph  = expf(dh) * h;
        dets[obase + 0] = fmaxf(pcx - 0.5f * pw, 0.0f);
        dets[obase + 1] = fmaxf(pcy - 0.5f * ph, 0.0f);
        dets[obase + 2] = fmaxf(pcx + 0.5f * pw - 1.0f, 0.0f);
        dets[obase + 3] = fmaxf(pcy + 0.5f * ph - 1.0f, 0.0f);
        dets[obase + 4] = s;
        sv[(size_t)(b * RR + i) * CM1 + j] = 1.0f;
    }
}

extern "C" void kernel_launch(void* const* d_in, const int* in_sizes, int n_in,
                              void* d_out, int out_size, void* d_ws, size_t ws_size,
                              hipStream_t stream) {
    const float* rois = (const float*)d_in[0];   // B*R*5
    const float* cls  = (const float*)d_in[1];   // B*R*81
    const float* bbox = (const float*)d_in[2];   // B*R*324

    float* out = (float*)d_out;
    const size_t sv_off   = (size_t)BB * RR * CM1 * 5;         // 25,600,000
    const size_t dist_off = sv_off + (size_t)BB * RR * CM1;    // 30,720,000
    const size_t maxs_off = dist_off + (size_t)BB * RR * CC;   // 35,904,000
    const size_t lab_off  = maxs_off + (size_t)BB * RR;        // 35,968,000

    float* dets   = out;
    float* sv     = out + sv_off;
    float* dist   = out + dist_off;
    float* maxs   = out + maxs_off;
    float* labels = out + lab_off;

    // Workspace: counts (2560*32 ints) + pairs (2560*896 float2)
    int*    counts = (int*)d_ws;
    float2* pairs  = (float2*)((char*)d_ws + (size_t)BB * CM1 * NTILE * sizeof(int));

    // K1: compact blocks first (they feed K2), then the BW-bound prep blocks.
    fused1_kernel<<<NTILES_TOTAL + (BB * RR) / 4, 256, 0, stream>>>(
        cls, dist, maxs, labels, (float4*)dets, counts, pairs);

    sort_decode_kernel<<<BB * CM1, 256, 0, stream>>>(
        rois, bbox, counts, pairs, dets, sv);
}

// Round 12
// 47.678 us; speedup vs baseline: 6.9171x; 1.0755x over previous
//
#include <hip/hip_runtime.h>
#include <hip/hip_bf16.h>
#include <math.h>

#define BB 32
#define RR 2000
#define CC 81
#define CM1 80
#define TROWS 64
#define NTILE 32            // tiles per batch (32 * 64 = 2048 >= 2000)
#define NTILES_TOTAL 1024   // BB * NTILE
#define CAP 28              // max stored pairs per (column, tile)
#define SCAP (NTILE * CAP)  // 896

// ---------------------------------------------------------------------------
// K1 (block-specialized): grid = 1024 compact-blocks + 16,000 prep-blocks.
//   compact (bid < 1024): stage 64-row tile in LDS, ballot-compact per class
//     -> counts/pairs. Latency-bound; overlaps prep's store stream.
//   prep (bid >= 1024): zero 480 float4 of dets+sv, 4 waves x 1 row softmax
//     -> dist/maxs/labels. BW-bound (the ~27 us floor).
// ---------------------------------------------------------------------------
__global__ __launch_bounds__(256) void fused1_kernel(
    const float* __restrict__ cls,   // (B, R, 81)
    float* __restrict__ dist,        // (B*R, 81)
    float* __restrict__ maxs,        // (B*R,)
    float* __restrict__ labels,      // (B*R,)
    float4* __restrict__ zbase,      // dets start: 30,720,000 floats to zero
    int* __restrict__ counts,        // (2560, NTILE)
    float2* __restrict__ pairs)      // (2560, SCAP)
{
    __shared__ float tile[CC * (TROWS + 1)];
    const int tid  = threadIdx.x;
    const int wave = tid >> 6;
    const int lane = tid & 63;

    if (blockIdx.x < NTILES_TOTAL) {
        // ---------------- compact path ----------------
        const int b   = blockIdx.x >> 5;
        const int tr  = blockIdx.x & 31;
        const int r0  = tr * TROWS;
        const int nr  = (RR - r0 < TROWS) ? (RR - r0) : TROWS;

        const float* src = cls + (size_t)(b * RR + r0) * CC;
        for (int i = tid; i < nr * CC; i += 256) {
            int rl = i / CC, c = i - rl * CC;
            tile[c * (TROWS + 1) + rl] = src[i];
        }
        __syncthreads();

        #pragma unroll 4
        for (int q = 0; q < 20; ++q) {
            const int c   = 1 + wave + 4 * q;          // classes 1..80
            const int col = b * CM1 + (c - 1);
            float s = tile[c * (TROWS + 1) + lane];
            bool valid = (lane < nr) && (s > 0.1f);
            unsigned long long mask = __ballot(valid);
            if (valid) {
                int pos = __popcll(mask & ((1ull << lane) - 1ull));
                if (pos < CAP)
                    pairs[(size_t)col * SCAP + tr * CAP + pos] =
                        make_float2(s, __int_as_float(r0 + lane));
            }
            if (lane == 0) {
                int cnt = (int)__popcll(mask);
                counts[col * NTILE + tr] = (cnt < CAP) ? cnt : CAP;
            }
        }
        return;
    }

    // ---------------- prep path ----------------
    const int pb = blockIdx.x - NTILES_TOTAL;   // 0..15999

    const float4 z4 = make_float4(0.0f, 0.0f, 0.0f, 0.0f);
    const int zb = pb * 480;
    zbase[zb + tid] = z4;
    if (tid < 224) zbase[zb + 256 + tid] = z4;

    const int row = pb * 4 + wave;

    const float* in = cls + (size_t)row * CC;
    float v0 = in[lane];
    float v1 = (lane < CC - 64) ? in[64 + lane] : -INFINITY;

    float m  = v0;
    int   mi = lane;
    if (v1 > m) { m = v1; mi = 64 + lane; }

    for (int off = 32; off > 0; off >>= 1) {
        float om  = __shfl_xor(m, off);
        int   omi = __shfl_xor(mi, off);
        if (om > m || (om == m && omi < mi)) { m = om; mi = omi; }
    }

    float e0 = expf(v0 - m);
    float e1 = (lane < CC - 64) ? expf(v1 - m) : 0.0f;
    float s  = e0 + e1;
    for (int off = 32; off > 0; off >>= 1) s += __shfl_xor(s, off);

    float inv = 1.0f / s;
    float* out = dist + (size_t)row * CC;
    out[lane] = e0 * inv;
    if (lane < CC - 64) out[64 + lane] = e1 * inv;
    if (lane == 0) {
        maxs[row]   = inv;
        labels[row] = (float)mi;
    }
}

// ---------------------------------------------------------------------------
// K2 (sort+decode): one 128-thread block per (b, class-1) column.
//   - counts loaded by lanes 0..31, wave-parallel exclusive scan (shfl_up)
//   - gather segments into LDS at prefix offsets (2 waves x 16 tiles)
//   - sort by (score desc, row asc): register bitonic (wave 0) if n <= 64,
//     LDS bitonic otherwise
//   - decode boxes, write valid prefix only (rest pre-zeroed by K1)
// ---------------------------------------------------------------------------
__global__ __launch_bounds__(128) void sort_decode_kernel(
    const float* __restrict__ rois,   // (B, R, 5)
    const float* __restrict__ bbox,   // (B, R, 4*C)
    const int* __restrict__ counts,   // (2560, NTILE)
    const float2* __restrict__ pairs, // (2560, SCAP)
    float* __restrict__ dets,         // (B, R, 80, 5), pre-zeroed
    float* __restrict__ sv)           // (B, R, 80), pre-zeroed
{
    __shared__ float ssc[1024];
    __shared__ int   sidx[1024];
    __shared__ int   scnt[NTILE];
    __shared__ int   spref[NTILE + 1];

    const int bj  = blockIdx.x;
    const int b   = bj / CM1;
    const int j   = bj % CM1;
    const int tid = threadIdx.x;
    const int wave = tid >> 6;
    const int lane = tid & 63;
    const int cls_col = j + 1;

    // Load 32 counts and scan them in wave 0 (lanes 0..31).
    if (wave == 0) {
        int c = (lane < NTILE) ? counts[bj * NTILE + lane] : 0;
        int x = c;
        #pragma unroll
        for (int off = 1; off < NTILE; off <<= 1) {
            int v = __shfl_up(x, off);
            if (lane >= off) x += v;
        }
        if (lane < NTILE) {
            scnt[lane]  = c;
            spref[lane] = x - c;            // exclusive prefix
            if (lane == NTILE - 1) spref[NTILE] = x;   // total
        }
    }
    __syncthreads();

    const int n = spref[NTILE];
    if (n == 0) return;

    const float2* pbase = pairs + (size_t)bj * SCAP;
    for (int t = wave; t < NTILE; t += 2) {
        int cnt = scnt[t];
        for (int k = lane; k < cnt; k += 64) {
            float2 e = pbase[t * CAP + k];
            int pos = spref[t] + k;
            ssc[pos]  = e.x;
            sidx[pos] = __float_as_int(e.y);
        }
    }
    __syncthreads();

    if (n > 1) {
        if (n <= 64) {
            if (wave == 0) {
                float s  = (lane < n) ? ssc[lane]  : -INFINITY;
                int   id = (lane < n) ? sidx[lane] : 0x7FFFFFFF;
                #pragma unroll
                for (int k = 2; k <= 64; k <<= 1) {
                    #pragma unroll
                    for (int jj = k >> 1; jj > 0; jj >>= 1) {
                        float os = __shfl_xor(s, jj);
                        int   oi = __shfl_xor(id, jj);
                        bool mineFirst = (s > os) || (s == os && id < oi);
                        bool iLower = ((lane & jj) == 0);
                        bool up = ((lane & k) == 0);
                        bool keep = up ? (mineFirst == iLower)
                                       : (mineFirst != iLower);
                        if (!keep) { s = os; id = oi; }
                    }
                }
                if (lane < n) { ssc[lane] = s; sidx[lane] = id; }
            }
            __syncthreads();
        } else {
            int n2 = 1;
            while (n2 < n) n2 <<= 1;
            for (int i = n + tid; i < n2; i += 128) {
                ssc[i]  = -INFINITY;
                sidx[i] = 0x7FFFFFFF;
            }
            __syncthreads();
            for (int k = 2; k <= n2; k <<= 1) {
                for (int jj = k >> 1; jj > 0; jj >>= 1) {
                    for (int i = tid; i < n2; i += 128) {
                        int ixj = i ^ jj;
                        if (ixj > i) {
                            float si = ssc[i], sx = ssc[ixj];
                            int   ii = sidx[i], ix = sidx[ixj];
                            bool before = (si > sx) || (si == sx && ii < ix);
                            bool doswap = ((i & k) == 0) ? !before : before;
                            if (doswap) {
                                ssc[i] = sx; ssc[ixj] = si;
                                sidx[i] = ix; sidx[ixj] = ii;
                            }
                        }
                    }
                    __syncthreads();
                }
            }
        }
    }

    for (int i = tid; i < n; i += 128) {
        size_t obase = ((size_t)(b * RR + i) * CM1 + j) * 5;
        int   r = sidx[i];
        float s = ssc[i];
        const float* rp = rois + (size_t)(b * RR + r) * 5;
        float x1 = rp[1], y1 = rp[2], x2 = rp[3], y2 = rp[4];
        float w  = x2 - x1 + 1.0f;
        float h  = y2 - y1 + 1.0f;
        float cx = x1 + 0.5f * w;
        float cy = y1 + 0.5f * h;
        const float* dp = bbox + (size_t)(b * RR + r) * (4 * CC) + 4 * cls_col;
        float dx = dp[0] * 0.1f, dy = dp[1] * 0.1f;
        float dw = dp[2] * 0.2f, dh = dp[3] * 0.2f;
        float pcx = dx * w + cx;
        float pcy = dy * h + cy;
        float pw  = expf(dw) * w;
        float ph  = expf(dh) * h;
        dets[obase + 0] = fmaxf(pcx - 0.5f * pw, 0.0f);
        dets[obase + 1] = fmaxf(pcy - 0.5f * ph, 0.0f);
        dets[obase + 2] = fmaxf(pcx + 0.5f * pw - 1.0f, 0.0f);
        dets[obase + 3] = fmaxf(pcy + 0.5f * ph - 1.0f, 0.0f);
        dets[obase + 4] = s;
        sv[(size_t)(b * RR + i) * CM1 + j] = 1.0f;
    }
}

extern "C" void kernel_launch(void* const* d_in, const int* in_sizes, int n_in,
                              void* d_out, int out_size, void* d_ws, size_t ws_size,
                              hipStream_t stream) {
    const float* rois = (const float*)d_in[0];   // B*R*5
    const float* cls  = (const float*)d_in[1];   // B*R*81
    const float* bbox = (const float*)d_in[2];   // B*R*324

    float* out = (float*)d_out;
    const size_t sv_off   = (size_t)BB * RR * CM1 * 5;         // 25,600,000
    const size_t dist_off = sv_off + (size_t)BB * RR * CM1;    // 30,720,000
    const size_t maxs_off = dist_off + (size_t)BB * RR * CC;   // 35,904,000
    const size_t lab_off  = maxs_off + (size_t)BB * RR;        // 35,968,000

    float* dets   = out;
    float* sv     = out + sv_off;
    float* dist   = out + dist_off;
    float* maxs   = out + maxs_off;
    float* labels = out + lab_off;

    // Workspace: counts (2560*32 ints) + pairs (2560*896 float2)
    int*    counts = (int*)d_ws;
    float2* pairs  = (float2*)((char*)d_ws + (size_t)BB * CM1 * NTILE * sizeof(int));

    // K1: compact blocks first (they feed K2), then the BW-bound prep blocks.
    fused1_kernel<<<NTILES_TOTAL + (BB * RR) / 4, 256, 0, stream>>>(
        cls, dist, maxs, labels, (float4*)dets, counts, pairs);

    sort_decode_kernel<<<BB * CM1, 128, 0, stream>>>(
        rois, bbox, counts, pairs, dets, sv);
}